// Round 1
// baseline (9317.497 us; speedup 1.0000x reference)
//
#include <hip/hip_runtime.h>
#include <hip/hip_bf16.h>

// ContextLSTM: B=128, T=512, I=1024, H=1024, C=512
// out tuple: out[B,T,H], h_f[B,H], c_f[B,H]  (fp32, concatenated in d_out)

typedef __attribute__((ext_vector_type(8))) short short8;   // 8 x bf16 (4 VGPRs)
typedef __attribute__((ext_vector_type(4))) float floatx4;  // MFMA accumulator
typedef unsigned short u16;
typedef unsigned int u32;

#define Bsz 128
#define Tsz 512
#define Isz 1024
#define Hsz 1024
#define G4  4096   // 4*H

__device__ __forceinline__ u16 f2bf(float f) {
    union { float f; u32 u; } v; v.f = f;
    u32 r = (v.u + 0x7fffu + ((v.u >> 16) & 1u)) >> 16;
    return (u16)r;
}
__device__ __forceinline__ float bf2f(u16 h) {
    union { u32 u; float f; } v; v.u = ((u32)h) << 16;
    return v.f;
}

// ---------------------------------------------------------------------------
// Cast Wi and Wh to bf16 (each 4H x K = 4194304 elements)
__global__ void k_cast_w(const float* __restrict__ Wi, const float* __restrict__ Wh,
                         u16* __restrict__ WiB, u16* __restrict__ WhB) {
    int i = blockIdx.x * 256 + threadIdx.x;   // grid covers 4194304
    WiB[i] = f2bf(Wi[i]);
    WhB[i] = f2bf(Wh[i]);
}

// Init recurrent state: hbuf[0] = bf16(h0), cws = c0   (131072 elements)
__global__ void k_state(const float* __restrict__ h0, const float* __restrict__ c0,
                        u16* __restrict__ hbuf0, float* __restrict__ cws) {
    int i = blockIdx.x * 256 + threadIdx.x;
    hbuf0[i] = f2bf(h0[i]);
    cws[i] = c0[i];
}

// ctxg[b,g] = ctx[b,:] . Wc[g,:] + bi[g] + bh[g] + bc[g]   (fp32, [B,4H])
__global__ void k_ctxg(const float* __restrict__ ctx, const float* __restrict__ Wc,
                       const float* __restrict__ bi, const float* __restrict__ bh,
                       const float* __restrict__ bc, float* __restrict__ ctxg) {
    int bid = blockIdx.x;               // 128*16 blocks
    int b = bid >> 4;
    int g = (bid & 15) * 256 + threadIdx.x;
    const float* wr = Wc + (long)g * 512;
    const float* cr = ctx + (long)b * 512;
    float s = 0.f;
    #pragma unroll 4
    for (int k = 0; k < 512; k += 4) {
        float4 w = *(const float4*)&wr[k];
        float4 c = *(const float4*)&cr[k];
        s += w.x * c.x + w.y * c.y + w.z * c.z + w.w * c.w;
    }
    ctxg[(long)b * G4 + g] = s + bi[g] + bh[g] + bc[g];
}

// ---------------------------------------------------------------------------
// Phase A: pre[r, g] = sum_k x[r,k]*Wi[g,k] + ctxg[r>>9, g]   (bf16 out)
// M=65536 (r = b*T+t), N=4096, K=1024. 128x128 tile, 4 waves of 64x64.
__global__ __launch_bounds__(256, 2)
void k_pre(const float* __restrict__ x, const u16* __restrict__ WiB,
           const float* __restrict__ ctxg, u16* __restrict__ pre) {
    const int bid = blockIdx.x;          // stripe*32 + nc ; 512*32 blocks
    const int stripe = bid >> 5, nc = bid & 31;
    const long m0 = (long)stripe * 128;
    const int n0 = nc * 128;
    const int tid = threadIdx.x;
    const int lane = tid & 63, wid = tid >> 6;
    const int wm = wid >> 1, wn = wid & 1;          // 2x2 waves

    __shared__ u16 As[128][72];   // 128 x 64 bf16, +8 pad
    __shared__ u16 Bs[128][72];

    floatx4 acc[4][4] = {};

    const int b = (int)(m0 >> 9);                  // batch (block never straddles)
    const int row = tid >> 1, half = tid & 1;
    const float* xsrc = x + (m0 + row) * Isz + half * 32;
    const u16*   wsrc = WiB + (long)(n0 + row) * Isz + half * 32;

    for (int kc = 0; kc < Isz; kc += 64) {
        // stage A: fp32 -> bf16
        const float4* xa = (const float4*)(xsrc + kc);
        #pragma unroll
        for (int j = 0; j < 8; j++) {
            float4 v = xa[j];
            u32 lo = (u32)f2bf(v.x) | ((u32)f2bf(v.y) << 16);
            u32 hi = (u32)f2bf(v.z) | ((u32)f2bf(v.w) << 16);
            *(uint2*)&As[row][half * 32 + j * 4] = make_uint2(lo, hi);
        }
        // stage B: bf16 copy
        const uint4* wa = (const uint4*)(wsrc + kc);
        uint4* bdst = (uint4*)&Bs[row][half * 32];
        #pragma unroll
        for (int j = 0; j < 4; j++) bdst[j] = wa[j];
        __syncthreads();

        #pragma unroll
        for (int kk = 0; kk < 64; kk += 32) {
            const int qr = lane & 15;
            const int qk = kk + (lane >> 4) * 8;
            short8 af[4], bfr[4];
            #pragma unroll
            for (int i2 = 0; i2 < 4; i2++)
                af[i2] = *(const short8*)&As[wm * 64 + i2 * 16 + qr][qk];
            #pragma unroll
            for (int j2 = 0; j2 < 4; j2++)
                bfr[j2] = *(const short8*)&Bs[wn * 64 + j2 * 16 + qr][qk];
            #pragma unroll
            for (int i2 = 0; i2 < 4; i2++)
                #pragma unroll
                for (int j2 = 0; j2 < 4; j2++)
                    acc[i2][j2] = __builtin_amdgcn_mfma_f32_16x16x32_bf16(
                        af[i2], bfr[j2], acc[i2][j2], 0, 0, 0);
        }
        __syncthreads();
    }

    // epilogue: + ctxg, store bf16.  D[m=quad*4+r][n=lane&15]
    const int q4 = (lane >> 4) * 4, qc = lane & 15;
    #pragma unroll
    for (int i2 = 0; i2 < 4; i2++) {
        #pragma unroll
        for (int j2 = 0; j2 < 4; j2++) {
            const int gc = n0 + wn * 64 + j2 * 16 + qc;
            const float cv = ctxg[(long)b * G4 + gc];
            const long grow = m0 + wm * 64 + i2 * 16 + q4;
            #pragma unroll
            for (int r = 0; r < 4; r++)
                pre[(grow + r) * G4 + gc] = f2bf(acc[i2][j2][r] + cv);
        }
    }
}

// ---------------------------------------------------------------------------
// Phase B step: gates = pre_t + h @ Wh^T, LSTM cell, write out/h/c.
// 256 blocks: mb(0..3) x nb(0..63). Block: 32 batches x 16 units (4 gate rows).
// Wave w handles gate group w (i,f,g,o). K=1024 in chunks of 128.
__global__ __launch_bounds__(256)
void k_step(const u16* __restrict__ pre, const u16* __restrict__ WhB,
            const u16* __restrict__ hcur, u16* __restrict__ hnext,
            float* __restrict__ cws, float* __restrict__ out,
            float* __restrict__ hf, float* __restrict__ cf, int tt) {
    const int bid = blockIdx.x;
    const int mb = bid >> 6, nb = bid & 63;
    const int b0 = mb * 32, u0 = nb * 16;
    const int tid = threadIdx.x, lane = tid & 63, wid = tid >> 6;

    __shared__ u16 Hs[32][136];    // 32 x 128 bf16 (+8 pad)
    __shared__ u16 Ws[64][136];    // 64 gate-cols x 128 bf16
    __shared__ float gbuf[4][32][16];

    floatx4 acc0 = {}, acc1 = {};

    const int hrow = tid >> 3, hoct = tid & 7;      // Hs: 32 rows x 8 thr (32B)
    const int wrow = tid >> 2, wq = tid & 3;        // Ws: 64 rows x 4 thr (64B)
    const int wgrp = wrow >> 4, wj = wrow & 15;
    const u16* hsrc = hcur + (long)(b0 + hrow) * Hsz + hoct * 16;
    const u16* wsrc = WhB + (long)(wgrp * Hsz + u0 + wj) * Hsz + wq * 32;

    for (int kc = 0; kc < Hsz; kc += 128) {
        const uint4* hs4 = (const uint4*)(hsrc + kc);
        uint4* hdst = (uint4*)&Hs[hrow][hoct * 16];
        hdst[0] = hs4[0]; hdst[1] = hs4[1];
        const uint4* ws4 = (const uint4*)(wsrc + kc);
        uint4* wdst = (uint4*)&Ws[wrow][wq * 32];
        #pragma unroll
        for (int j = 0; j < 4; j++) wdst[j] = ws4[j];
        __syncthreads();

        #pragma unroll
        for (int kk = 0; kk < 128; kk += 32) {
            const int qr = lane & 15;
            const int qk = kk + (lane >> 4) * 8;
            short8 a0 = *(const short8*)&Hs[qr][qk];
            short8 a1 = *(const short8*)&Hs[16 + qr][qk];
            short8 bfr = *(const short8*)&Ws[wid * 16 + qr][qk];
            acc0 = __builtin_amdgcn_mfma_f32_16x16x32_bf16(a0, bfr, acc0, 0, 0, 0);
            acc1 = __builtin_amdgcn_mfma_f32_16x16x32_bf16(a1, bfr, acc1, 0, 0, 0);
        }
        __syncthreads();
    }

    // add pre, activate, stash to LDS
    const int q4 = (lane >> 4) * 4, qc = lane & 15;
    #pragma unroll
    for (int mi = 0; mi < 2; mi++) {
        floatx4 a = mi ? acc1 : acc0;
        #pragma unroll
        for (int r = 0; r < 4; r++) {
            const int brow = mi * 16 + q4 + r;
            const long pidx = ((long)(b0 + brow) * Tsz + tt) * G4 + wid * Hsz + u0 + qc;
            float g = a[r] + bf2f(pre[pidx]);
            g = (wid == 2) ? tanhf(g) : 1.f / (1.f + __expf(-g));
            gbuf[wid][brow][qc] = g;
        }
    }
    __syncthreads();

    // elementwise LSTM cell on the block's 32x16 patch
    for (int e = tid; e < 512; e += 256) {
        const int brow = e >> 4, u = e & 15;
        const int bb = b0 + brow, un = u0 + u;
        const float ig = gbuf[0][brow][u];
        const float fg = gbuf[1][brow][u];
        const float gg = gbuf[2][brow][u];
        const float og = gbuf[3][brow][u];
        const long ci = (long)bb * Hsz + un;
        const float cn = fg * cws[ci] + ig * gg;
        const float hn = og * tanhf(cn);
        cws[ci] = cn;
        hnext[ci] = f2bf(hn);
        out[((long)bb * Tsz + tt) * Hsz + un] = hn;
        if (tt == 511) { hf[ci] = hn; cf[ci] = cn; }
    }
}

// ---------------------------------------------------------------------------
extern "C" void kernel_launch(void* const* d_in, const int* in_sizes, int n_in,
                              void* d_out, int out_size, void* d_ws, size_t ws_size,
                              hipStream_t stream) {
    const float* x   = (const float*)d_in[0];
    const float* h0  = (const float*)d_in[1];
    const float* c0  = (const float*)d_in[2];
    const float* ctx = (const float*)d_in[3];
    const float* Wi  = (const float*)d_in[4];
    const float* bi  = (const float*)d_in[5];
    const float* Wh  = (const float*)d_in[6];
    const float* bh  = (const float*)d_in[7];
    const float* Wc  = (const float*)d_in[8];
    const float* bc  = (const float*)d_in[9];

    float* out = (float*)d_out;
    float* hf  = out + (size_t)Bsz * Tsz * Hsz;   // 67108864
    float* cf  = hf + (size_t)Bsz * Hsz;

    char* ws = (char*)d_ws;
    u16*   pre  = (u16*)(ws);                       // 536870912 B
    u16*   WiB  = (u16*)(ws + 536870912ull);        //   8388608 B
    u16*   WhB  = (u16*)(ws + 545259520ull);        //   8388608 B
    float* ctxg = (float*)(ws + 553648128ull);      //   2097152 B
    u16*   hbuf = (u16*)(ws + 555745280ull);        // 2x 262144 B
    float* cws  = (float*)(ws + 556269568ull);      //    524288 B
    // total 556793856 B

    k_cast_w<<<16384, 256, 0, stream>>>(Wi, Wh, WiB, WhB);
    k_state<<<512, 256, 0, stream>>>(h0, c0, hbuf, cws);
    k_ctxg<<<2048, 256, 0, stream>>>(ctx, Wc, bi, bh, bc, ctxg);
    k_pre<<<16384, 256, 0, stream>>>(x, WiB, ctxg, pre);

    for (int tt = 0; tt < 512; tt++) {
        const u16* hc = hbuf + (size_t)(tt & 1) * (Bsz * Hsz);
        u16*       hn = hbuf + (size_t)((tt + 1) & 1) * (Bsz * Hsz);
        k_step<<<256, 256, 0, stream>>>(pre, WhB, hc, hn, cws, out, hf, cf, tt);
    }
}